// Round 1
// baseline (1087.700 us; speedup 1.0000x reference)
//
#include <hip/hip_runtime.h>

// ---- output layout (floats) ----
#define LOSS_OFF  8388608
#define IDX_OFF   8388609
#define NCS_OFF   8454145
#define EMAW_OFF  8454657
#define EMB_OFF   8520193

// ---- workspace layout (float offsets) ----
#define WS_DW     0        // 512*128 = 65536 floats
#define WS_COUNTS 65536    // 512
#define WS_SUMS   66048    // 16 (commit, ent)
#define WS_EE     66064    // 512 (||e_k||^2)
#define WS_INVS   66576    // 512 (1/smoothed)

// ||e_k||^2 precompute: grid 8 x 256, wave handles 16 codewords
__global__ __launch_bounds__(256) void ee_kernel(const float* __restrict__ emb,
                                                 float* __restrict__ ee) {
  int lane = threadIdx.x & 63;
  int wave = threadIdx.x >> 6;
  int kbase = (blockIdx.x * 4 + wave) * 16;
  for (int i = 0; i < 16; ++i) {
    int k = kbase + i;
    float2 v = *(const float2*)(emb + (size_t)k * 128 + lane * 2);
    float p = v.x * v.x + v.y * v.y;
    #pragma unroll
    for (int o = 32; o; o >>= 1) p += __shfl_xor(p, o);
    if (lane == 0) ee[k] = p;
  }
}

// distances + argmin + softmax-entropy + EMA scatter.
// block = 256 thr (4 waves), 32 rows/block (8 rows/wave), grid 2048.
__global__ __launch_bounds__(256, 3) void dist_kernel(
    const float* __restrict__ inputs, const float* __restrict__ emb,
    const float* __restrict__ ee, float* __restrict__ out,
    float* __restrict__ dw, float* __restrict__ counts, float* __restrict__ sums)
{
  __shared__ float xs[32][132];       // x tile, all 128 c resident (+pad)
  __shared__ float eTf[32 * 260];     // codebook chunk, transposed [c][k], stride 260
  __shared__ float red[8];
  const int t    = threadIdx.x;
  const int lane = t & 63;
  const int wave = t >> 6;
  const int n0   = blockIdx.x * 32;
  const int b    = n0 >> 15;          // 32768 spatial per batch
  const int s0   = n0 & 32767;

  // stage x: thread t -> row t&31, c-slice (t>>5)*16
  {
    const int r  = t & 31;
    const int c0 = (t >> 5) * 16;
    const float* src = inputs + ((size_t)b * 128) * 32768 + s0 + r;
    #pragma unroll
    for (int i = 0; i < 16; ++i) xs[r][c0 + i] = src[(size_t)(c0 + i) * 32768];
  }
  __syncthreads();

  // ||x_r||^2 per wave-row (wave-uniform after butterfly)
  float xx[8];
  #pragma unroll
  for (int r = 0; r < 8; ++r) {
    float2 v = *(const float2*)&xs[wave * 8 + r][lane * 2];
    float p = v.x * v.x + v.y * v.y;
    #pragma unroll
    for (int o = 32; o; o >>= 1) p += __shfl_xor(p, o);
    xx[r] = p;
  }

  float acc[8][8];   // [row][kc*4+j], lane's k = kc*256 + 4*lane + j
  #pragma unroll
  for (int r = 0; r < 8; ++r)
    #pragma unroll
    for (int q = 0; q < 8; ++q) acc[r][q] = 0.f;

  #pragma unroll
  for (int kc = 0; kc < 2; ++kc) {
    for (int cc = 0; cc < 4; ++cc) {
      __syncthreads();
      // stage eT chunk: 256 k x 32 c, transposed into [c][k] stride 260
      #pragma unroll
      for (int i = 0; i < 8; ++i) {
        int g = t + 256 * i;          // 2048 granules
        int kk = g >> 3, cg = g & 7;
        float4 v = *(const float4*)(emb + (size_t)(kc * 256 + kk) * 128 + cc * 32 + cg * 4);
        float* dst = &eTf[(cg * 4) * 260 + kk];
        dst[0] = v.x; dst[260] = v.y; dst[520] = v.z; dst[780] = v.w;
      }
      __syncthreads();
      for (int c4 = 0; c4 < 8; ++c4) {
        const float* eb = &eTf[(c4 * 4) * 260 + 4 * lane];
        float4 e0 = *(const float4*)(eb);
        float4 e1 = *(const float4*)(eb + 260);
        float4 e2 = *(const float4*)(eb + 520);
        float4 e3 = *(const float4*)(eb + 780);
        const float* xb = &xs[wave * 8][cc * 32 + c4 * 4];
        #pragma unroll
        for (int r = 0; r < 8; ++r) {
          float4 xv = *(const float4*)(xb + r * 132);
          acc[r][kc * 4 + 0] += xv.x * e0.x + xv.y * e1.x + xv.z * e2.x + xv.w * e3.x;
          acc[r][kc * 4 + 1] += xv.x * e0.y + xv.y * e1.y + xv.z * e2.y + xv.w * e3.y;
          acc[r][kc * 4 + 2] += xv.x * e0.z + xv.y * e1.z + xv.z * e2.z + xv.w * e3.z;
          acc[r][kc * 4 + 3] += xv.x * e0.w + xv.y * e1.w + xv.z * e2.w + xv.w * e3.w;
        }
      }
    }
  }

  float eev[8];
  *(float4*)&eev[0] = *(const float4*)(ee + 4 * lane);
  *(float4*)&eev[4] = *(const float4*)(ee + 256 + 4 * lane);

  float commit_acc = 0.f, ent_acc = 0.f;
  #pragma unroll
  for (int r = 0; r < 8; ++r) {
    float d[8];
    float bd = 3.4e38f; int bk = 0x7fffffff;
    #pragma unroll
    for (int kc2 = 0; kc2 < 2; ++kc2) {
      #pragma unroll
      for (int j = 0; j < 4; ++j) {
        int q = kc2 * 4 + j;
        float dd = xx[r] + eev[q] - 2.f * acc[r][q];
        d[q] = dd;
        int kg = kc2 * 256 + 4 * lane + j;
        if (dd < bd || (dd == bd && kg < bk)) { bd = dd; bk = kg; }
      }
    }
    #pragma unroll
    for (int o = 32; o; o >>= 1) {       // argmin, smaller index wins ties
      float od = __shfl_xor(bd, o);
      int   ok = __shfl_xor(bk, o);
      if (od < bd || (od == bd && ok < bk)) { bd = od; bk = ok; }
    }
    // softmax(-d): z - zmax = bd - d  (bd = d_min)
    float s = 0.f;
    #pragma unroll
    for (int q = 0; q < 8; ++q) { float e = __expf(bd - d[q]); d[q] = e; s += e; }
    #pragma unroll
    for (int o = 32; o; o >>= 1) s += __shfl_xor(s, o);
    float inv_s = 1.f / s;
    float ent = 0.f;
    #pragma unroll
    for (int q = 0; q < 8; ++q) { float p = d[q] * inv_s; ent += p * __logf(p + 1e-8f); }
    #pragma unroll
    for (int o = 32; o; o >>= 1) ent += __shfl_xor(ent, o);

    int row_n = n0 + wave * 8 + r;
    if (lane == 0) {
      out[IDX_OFF + row_n] = (float)bk;
      commit_acc += bd;                 // d_min == ||x - e_idx||^2
      ent_acc    += ent;
      unsafeAtomicAdd(&counts[bk], 1.f);
    }
    // dw[bk][:] += x_r  (bk wave-uniform; 2 floats/lane)
    float2 xv2 = *(const float2*)&xs[wave * 8 + r][lane * 2];
    unsafeAtomicAdd(&dw[bk * 128 + 2 * lane],     xv2.x);
    unsafeAtomicAdd(&dw[bk * 128 + 2 * lane + 1], xv2.y);
  }
  if (lane == 0) { red[wave] = commit_acc; red[4 + wave] = ent_acc; }
  __syncthreads();
  if (t == 0) {
    unsafeAtomicAdd(&sums[0], red[0] + red[1] + red[2] + red[3]);
    unsafeAtomicAdd(&sums[1], red[4] + red[5] + red[6] + red[7]);
  }
}

// quantized gather: block = 64 spatial x 128 c, LDS transposed for coalesced writes
__global__ __launch_bounds__(256) void gather_kernel(const float* __restrict__ emb,
                                                     float* __restrict__ out)
{
  __shared__ float eq[128 * 64];   // [c][s]
  const int t  = threadIdx.x;
  const int n0 = blockIdx.x * 64;
  const int b  = n0 >> 15;
  const int s0 = n0 & 32767;
  {
    const int r  = t >> 2;         // local spatial 0..63
    const int qq = t & 3;
    const int kidx = (int)out[IDX_OFF + n0 + r];
    const float* src = emb + (size_t)kidx * 128;
    #pragma unroll
    for (int i = 0; i < 8; ++i) {
      int g = qq + 4 * i;          // float4 granule within the row
      float4 v = *(const float4*)(src + g * 4);
      float* dst = &eq[(g * 4) * 64 + r];
      dst[0] = v.x; dst[64] = v.y; dst[128] = v.z; dst[192] = v.w;
    }
  }
  __syncthreads();
  {
    const int sl = (t & 15) * 4;
    const int cb = t >> 4;
    #pragma unroll
    for (int j = 0; j < 8; ++j) {
      int c = cb + 16 * j;
      float4 v = *(const float4*)&eq[c * 64 + sl];
      *(float4*)(out + ((size_t)b * 128 + c) * 32768 + s0 + sl) = v;
    }
  }
}

// finalize scalars: new_cluster_size, inv smoothed, loss
__global__ __launch_bounds__(512) void c1_kernel(const float* __restrict__ ecs,
    const float* __restrict__ counts, const float* __restrict__ sums,
    float* __restrict__ invs, float* __restrict__ out)
{
  __shared__ float sred[512];
  int t = threadIdx.x;
  float cn = 0.99f * ecs[t] + 0.01f * counts[t];
  out[NCS_OFF + t] = cn;
  sred[t] = cn;
  __syncthreads();
  for (int o = 256; o; o >>= 1) {
    if (t < o) sred[t] += sred[t + o];
    __syncthreads();
  }
  float ntot = sred[0];
  float sm = (cn + 1e-5f) / (ntot + 0.00512f) * ntot;
  invs[t] = 1.f / sm;
  if (t == 0)
    out[LOSS_OFF] = 0.25f * sums[0] / 8388608.f - 0.01f * sums[1] / 65536.f;
}

// elementwise EMA weight update + normalized embedding
__global__ __launch_bounds__(256) void c2_kernel(const float* __restrict__ emaw,
    const float* __restrict__ dw, const float* __restrict__ invs,
    float* __restrict__ out)
{
  int i = blockIdx.x * 256 + threadIdx.x;   // 0..65535
  float val = 0.99f * emaw[i] + 0.01f * dw[i];
  out[EMAW_OFF + i] = val;
  out[EMB_OFF + i] = val * invs[i >> 7];
}

extern "C" void kernel_launch(void* const* d_in, const int* in_sizes, int n_in,
                              void* d_out, int out_size, void* d_ws, size_t ws_size,
                              hipStream_t stream) {
  const float* inputs = (const float*)d_in[0];
  const float* emb    = (const float*)d_in[1];
  const float* ecs    = (const float*)d_in[2];
  const float* emaw   = (const float*)d_in[3];
  float* out = (float*)d_out;
  float* wsf = (float*)d_ws;
  float* dw     = wsf + WS_DW;
  float* counts = wsf + WS_COUNTS;
  float* sums   = wsf + WS_SUMS;
  float* ee     = wsf + WS_EE;
  float* invs   = wsf + WS_INVS;
  (void)in_sizes; (void)n_in; (void)out_size; (void)ws_size;

  hipMemsetAsync(d_ws, 0, (WS_SUMS + 16) * sizeof(float), stream);
  ee_kernel    <<<8,    256, 0, stream>>>(emb, ee);
  dist_kernel  <<<2048, 256, 0, stream>>>(inputs, emb, ee, out, dw, counts, sums);
  gather_kernel<<<1024, 256, 0, stream>>>(emb, out);
  c1_kernel    <<<1,    512, 0, stream>>>(ecs, counts, sums, invs, out);
  c2_kernel    <<<256,  256, 0, stream>>>(emaw, dw, invs, out);
}

// Round 2
// 418.753 us; speedup vs baseline: 2.5975x; 2.5975x over previous
//
#include <hip/hip_runtime.h>

// ---- output layout (floats) ----
#define LOSS_OFF  8388608
#define IDX_OFF   8388609
#define NCS_OFF   8454145
#define EMAW_OFF  8454657
#define EMB_OFF   8520193

__device__ __forceinline__ float rdl(float v, int l) {
  return __int_as_float(__builtin_amdgcn_readlane(__float_as_int(v), l));
}

// ||e_k||^2 precompute
__global__ __launch_bounds__(256) void ee_kernel(const float* __restrict__ emb,
                                                 float* __restrict__ ee) {
  int lane = threadIdx.x & 63;
  int wave = threadIdx.x >> 6;
  int kbase = (blockIdx.x * 4 + wave) * 16;
  for (int i = 0; i < 16; ++i) {
    int k = kbase + i;
    float2 v = *(const float2*)(emb + (size_t)k * 128 + lane * 2);
    float p = v.x * v.x + v.y * v.y;
    #pragma unroll
    for (int o = 32; o; o >>= 1) p += __shfl_xor(p, o);
    if (lane == 0) ee[k] = p;
  }
}

// distances + argmin + softmax-entropy. Lane owns k = 8*lane + j.
// x broadcast via readlane->SGPR (no LDS reads for x in the hot loop).
// es layout: channel-column pc, position kpos = k + 4*(k>>5)  (bank stagger).
__global__ __launch_bounds__(256, 4) void dist_kernel(
    const float* __restrict__ inputs, const float* __restrict__ emb,
    const float* __restrict__ ee, float* __restrict__ out,
    float* __restrict__ idxws, float* __restrict__ sums)
{
  __shared__ float smem[16 * 584];   // es: 37.4 KB; xs aliases the front (4224 fl)
  __shared__ float red[8];
  float* es = smem;
  float* xs = smem;                  // [32][132] during x staging only

  const int t = threadIdx.x, lane = t & 63, wave = t >> 6;
  const int n0 = blockIdx.x * 32;
  const int b = n0 >> 15, s0 = n0 & 32767;

  // stage x tile (coalesced 128B segments)
  {
    const int r = t & 31, c0 = (t >> 5) * 16;
    const float* src = inputs + (size_t)b * 128 * 32768 + s0 + r;
    #pragma unroll
    for (int i = 0; i < 16; ++i)
      xs[r * 132 + c0 + i] = src[(size_t)(c0 + i) * 32768];
  }
  __syncthreads();

  // pull x to per-lane regs: xv[2r+h] at lane m == x[r][h*64+m]
  float xv[16];
  #pragma unroll
  for (int r = 0; r < 8; ++r) {
    xv[2*r]   = xs[(wave*8 + r) * 132 + lane];
    xv[2*r+1] = xs[(wave*8 + r) * 132 + 64 + lane];
  }
  float xx[8];
  #pragma unroll
  for (int r = 0; r < 8; ++r) {
    float p = xv[2*r]*xv[2*r] + xv[2*r+1]*xv[2*r+1];
    #pragma unroll
    for (int o = 32; o; o >>= 1) p += __shfl_xor(p, o);
    xx[r] = p;
  }

  float acc[8][8];
  #pragma unroll
  for (int r = 0; r < 8; ++r)
    #pragma unroll
    for (int j = 0; j < 8; ++j) acc[r][j] = 0.f;

  const int lofs = 8 * lane + 4 * (lane >> 2);   // kpos(8*lane) .. +7 contiguous

  #pragma unroll
  for (int h = 0; h < 2; ++h) {
    for (int ch2 = 0; ch2 < 4; ++ch2) {
      const int cb = h * 64 + ch2 * 16;
      __syncthreads();
      // stage es: 512 k x 16 c. granule: k = g>>2, m4 = g&3 (coalesced global).
      // component mm -> physical column m4 + 4*mm  (conflict-free ds writes)
      #pragma unroll
      for (int i = 0; i < 8; ++i) {
        int g = t + 256 * i;
        int k = g >> 2, m4 = g & 3;
        int kpos = k + 4 * (k >> 5);
        float4 v = *(const float4*)(emb + (size_t)k * 128 + cb + m4 * 4);
        es[(m4 +  0) * 584 + kpos] = v.x;
        es[(m4 +  4) * 584 + kpos] = v.y;
        es[(m4 +  8) * 584 + kpos] = v.z;
        es[(m4 + 12) * 584 + kpos] = v.w;
      }
      __syncthreads();
      for (int pc = 0; pc < 16; ++pc) {
        float4 a4 = *(const float4*)&es[pc * 584 + lofs];
        float4 b4 = *(const float4*)&es[pc * 584 + lofs + 4];
        const int cl = (pc & 3) * 4 + (pc >> 2);   // logical channel in chunk
        const int li = ch2 * 16 + cl;              // readlane index (uniform)
        #pragma unroll
        for (int r = 0; r < 8; ++r) {
          float sx = rdl(xv[2*r + h], li);
          acc[r][0] += sx * a4.x; acc[r][1] += sx * a4.y;
          acc[r][2] += sx * a4.z; acc[r][3] += sx * a4.w;
          acc[r][4] += sx * b4.x; acc[r][5] += sx * b4.y;
          acc[r][6] += sx * b4.z; acc[r][7] += sx * b4.w;
        }
      }
    }
  }

  float eev[8];
  *(float4*)&eev[0] = *(const float4*)(ee + 8 * lane);
  *(float4*)&eev[4] = *(const float4*)(ee + 8 * lane + 4);

  float commit_acc = 0.f, ent_acc = 0.f;
  #pragma unroll
  for (int r = 0; r < 8; ++r) {
    float d[8];
    float bd = 3.4e38f; int bk = 0;
    #pragma unroll
    for (int j = 0; j < 8; ++j) {
      float dd = xx[r] + eev[j] - 2.f * acc[r][j];
      d[j] = dd;
      if (dd < bd) { bd = dd; bk = 8 * lane + j; }   // j asc -> smallest k kept
    }
    #pragma unroll
    for (int o = 32; o; o >>= 1) {
      float od = __shfl_xor(bd, o); int ok = __shfl_xor(bk, o);
      if (od < bd || (od == bd && ok < bk)) { bd = od; bk = ok; }
    }
    float ssum = 0.f;
    #pragma unroll
    for (int j = 0; j < 8; ++j) { float e = __expf(bd - d[j]); d[j] = e; ssum += e; }
    #pragma unroll
    for (int o = 32; o; o >>= 1) ssum += __shfl_xor(ssum, o);
    float inv_s = 1.f / ssum;
    float ent = 0.f;
    #pragma unroll
    for (int j = 0; j < 8; ++j) { float p = d[j] * inv_s; ent += p * __logf(p + 1e-8f); }
    #pragma unroll
    for (int o = 32; o; o >>= 1) ent += __shfl_xor(ent, o);
    if (lane == 0) {
      int rn = n0 + wave * 8 + r;
      out[IDX_OFF + rn] = (float)bk;
      idxws[rn] = (float)bk;
      commit_acc += bd;
      ent_acc    += ent;
    }
  }
  if (lane == 0) { red[wave] = commit_acc; red[4 + wave] = ent_acc; }
  __syncthreads();
  if (t == 0) {
    unsafeAtomicAdd(&sums[0], red[0] + red[1] + red[2] + red[3]);
    unsafeAtomicAdd(&sums[1], red[4] + red[5] + red[6] + red[7]);
  }
}

// dw scatter via LDS accumulation: block = (row-split s, 16-channel slice ccB).
__global__ __launch_bounds__(256) void scatter_kernel(
    const float* __restrict__ inputs, const float* __restrict__ idxws,
    float* __restrict__ partial, float* __restrict__ cpart, int S)
{
  __shared__ float acc[512 * 17];
  __shared__ float cnts[512];
  const int t = threadIdx.x;
  const int s = blockIdx.x >> 3, ccB = blockIdx.x & 7;
  const int R = 65536 / S;
  for (int m = t; m < 512 * 17; m += 256) acc[m] = 0.f;
  if (ccB == 0) for (int m = t; m < 512; m += 256) cnts[m] = 0.f;
  __syncthreads();
  const int l = t & 63, cg = t >> 6;
  for (int it = 0; it < R / 256; ++it) {
    int n = s * R + it * 256;
    int bb = n >> 15;
    int sp = (n & 32767) + 4 * l;
    float4 i4 = *(const float4*)(idxws + n + 4 * l);
    int k0 = (int)i4.x, k1 = (int)i4.y, k2 = (int)i4.z, k3 = (int)i4.w;
    #pragma unroll
    for (int ci = 0; ci < 4; ++ci) {
      int c = cg * 4 + ci;
      float4 x4 = *(const float4*)(inputs + ((size_t)bb * 128 + ccB * 16 + c) * 32768 + sp);
      atomicAdd(&acc[k0 * 17 + c], x4.x);
      atomicAdd(&acc[k1 * 17 + c], x4.y);
      atomicAdd(&acc[k2 * 17 + c], x4.z);
      atomicAdd(&acc[k3 * 17 + c], x4.w);
    }
    if (ccB == 0 && cg == 0) {
      atomicAdd(&cnts[k0], 1.f); atomicAdd(&cnts[k1], 1.f);
      atomicAdd(&cnts[k2], 1.f); atomicAdd(&cnts[k3], 1.f);
    }
  }
  __syncthreads();
  for (int m = t; m < 512 * 16; m += 256) {
    int k = m >> 4, c = m & 15;
    partial[(size_t)s * 65536 + k * 128 + ccB * 16 + c] = acc[k * 17 + c];
  }
  if (ccB == 0) for (int m = t; m < 512; m += 256) cpart[s * 512 + m] = cnts[m];
}

// quantized gather: 64 spatial x 128 c per block, LDS transpose, coalesced writes
__global__ __launch_bounds__(256) void gather_kernel(const float* __restrict__ emb,
                                                     float* __restrict__ out)
{
  __shared__ float eq[128 * 64];   // [c][s]
  const int t  = threadIdx.x;
  const int n0 = blockIdx.x * 64;
  const int b  = n0 >> 15;
  const int s0 = n0 & 32767;
  {
    const int r  = t >> 2;
    const int qq = t & 3;
    const int kidx = (int)out[IDX_OFF + n0 + r];
    const float* src = emb + (size_t)kidx * 128;
    #pragma unroll
    for (int i = 0; i < 8; ++i) {
      int g = qq + 4 * i;
      float4 v = *(const float4*)(src + g * 4);
      float* dst = &eq[(g * 4) * 64 + r];
      dst[0] = v.x; dst[64] = v.y; dst[128] = v.z; dst[192] = v.w;
    }
  }
  __syncthreads();
  {
    const int sl = (t & 15) * 4;
    const int cb = t >> 4;
    #pragma unroll
    for (int j = 0; j < 8; ++j) {
      int c = cb + 16 * j;
      float4 v = *(const float4*)&eq[c * 64 + sl];
      *(float4*)(out + ((size_t)b * 128 + c) * 32768 + s0 + sl) = v;
    }
  }
}

// finalize scalars
__global__ __launch_bounds__(512) void c1_kernel(const float* __restrict__ ecs,
    const float* __restrict__ cpart, const float* __restrict__ sums,
    float* __restrict__ invs, float* __restrict__ out, int S)
{
  __shared__ float sred[512];
  int t = threadIdx.x;
  float cnt = 0.f;
  for (int s = 0; s < S; ++s) cnt += cpart[s * 512 + t];
  float cn = 0.99f * ecs[t] + 0.01f * cnt;
  out[NCS_OFF + t] = cn;
  sred[t] = cn;
  __syncthreads();
  for (int o = 256; o; o >>= 1) {
    if (t < o) sred[t] += sred[t + o];
    __syncthreads();
  }
  float ntot = sred[0];
  float sm = (cn + 1e-5f) / (ntot + 0.00512f) * ntot;
  invs[t] = 1.f / sm;
  if (t == 0)
    out[LOSS_OFF] = 0.25f * sums[0] / 8388608.f - 0.01f * sums[1] / 65536.f;
}

// EMA weight update + normalized embedding (reduces S partials)
__global__ __launch_bounds__(256) void c2_kernel(const float* __restrict__ emaw,
    const float* __restrict__ partial, const float* __restrict__ invs,
    float* __restrict__ out, int S)
{
  int i = blockIdx.x * 256 + threadIdx.x;
  float dwv = 0.f;
  for (int s = 0; s < S; ++s) dwv += partial[(size_t)s * 65536 + i];
  float val = 0.99f * emaw[i] + 0.01f * dwv;
  out[EMAW_OFF + i] = val;
  out[EMB_OFF + i] = val * invs[i >> 7];
}

extern "C" void kernel_launch(void* const* d_in, const int* in_sizes, int n_in,
                              void* d_out, int out_size, void* d_ws, size_t ws_size,
                              hipStream_t stream) {
  const float* inputs = (const float*)d_in[0];
  const float* emb    = (const float*)d_in[1];
  const float* ecs    = (const float*)d_in[2];
  const float* emaw   = (const float*)d_in[3];
  float* out = (float*)d_out;
  float* wsf = (float*)d_ws;
  (void)in_sizes; (void)n_in; (void)out_size;

  size_t wsfl = ws_size / 4;
  int S = 16;
  while (S > 1 && (size_t)S * 66048 + 66592 > wsfl) S >>= 1;

  float* partial = wsf;
  float* cpart   = partial + (size_t)S * 65536;
  float* idxws   = cpart + S * 512;
  float* sums    = idxws + 65536;
  float* ee      = sums + 16;
  float* invs    = ee + 512;

  hipMemsetAsync(sums, 0, 16 * sizeof(float), stream);
  ee_kernel     <<<8,     256, 0, stream>>>(emb, ee);
  dist_kernel   <<<2048,  256, 0, stream>>>(inputs, emb, ee, out, idxws, sums);
  scatter_kernel<<<8 * S, 256, 0, stream>>>(inputs, idxws, partial, cpart, S);
  gather_kernel <<<1024,  256, 0, stream>>>(emb, out);
  c1_kernel     <<<1,     512, 0, stream>>>(ecs, cpart, sums, invs, out, S);
  c2_kernel     <<<256,   256, 0, stream>>>(emaw, partial, invs, out, S);
}

// Round 3
// 374.092 us; speedup vs baseline: 2.9076x; 1.1194x over previous
//
#include <hip/hip_runtime.h>

// ---- output layout (floats) ----
#define LOSS_OFF  8388608
#define IDX_OFF   8388609
#define NCS_OFF   8454145
#define EMAW_OFF  8454657
#define EMB_OFF   8520193

__device__ __forceinline__ float rdl(float v, int l) {
  return __int_as_float(__builtin_amdgcn_readlane(__float_as_int(v), l));
}

// ||e_k||^2 precompute
__global__ __launch_bounds__(256) void ee_kernel(const float* __restrict__ emb,
                                                 float* __restrict__ ee) {
  int lane = threadIdx.x & 63;
  int wave = threadIdx.x >> 6;
  int kbase = (blockIdx.x * 4 + wave) * 16;
  for (int i = 0; i < 16; ++i) {
    int k = kbase + i;
    float2 v = *(const float2*)(emb + (size_t)k * 128 + lane * 2);
    float p = v.x * v.x + v.y * v.y;
    #pragma unroll
    for (int o = 32; o; o >>= 1) p += __shfl_xor(p, o);
    if (lane == 0) ee[k] = p;
  }
}

// distances + argmin + fused-entropy softmax + quantized gather.
// K processed in 2 halves of 256; lane owns k = 256h + 4*lane + j.
// acc[8][4] = 32 VGPRs. x broadcast via readlane (no LDS in hot loop for x).
// es: [32 phys cols][292], kpos = k + 4*(k>>5)  -> conflict-free writes+b128 reads.
__global__ __launch_bounds__(256, 4) void dist_kernel(
    const float* __restrict__ inputs, const float* __restrict__ emb,
    const float* __restrict__ ee, float* __restrict__ out,
    float* __restrict__ idxws, float* __restrict__ sums)
{
  __shared__ float smem[32 * 292];   // es (37.4 KB); xs/eq alias front [32][132]
  __shared__ float red[8];
  __shared__ int   ibk[32];
  float* es = smem;
  float* xs = smem;

  const int t = threadIdx.x, lane = t & 63, wave = t >> 6;
  const int n0 = blockIdx.x * 32;
  const int b = n0 >> 15, s0 = n0 & 32767;

  // stage x tile [row][c]
  {
    const int r = t & 31, c0 = (t >> 5) * 16;
    const float* src = inputs + (size_t)b * 128 * 32768 + s0 + r;
    #pragma unroll
    for (int i = 0; i < 16; ++i)
      xs[r * 132 + c0 + i] = src[(size_t)(c0 + i) * 32768];
  }
  __syncthreads();

  // xv[2r+h] at lane m == x[row r][h*64+m]
  float xv[16];
  #pragma unroll
  for (int r = 0; r < 8; ++r) {
    xv[2*r]   = xs[(wave*8 + r) * 132 + lane];
    xv[2*r+1] = xs[(wave*8 + r) * 132 + 64 + lane];
  }

  const int lofs = 4 * lane + 4 * (lane >> 3);
  float m0[8], S0[8], T0[8]; int bk0[8];

  for (int h = 0; h < 2; ++h) {
    float acc[8][4];
    #pragma unroll
    for (int r = 0; r < 8; ++r)
      #pragma unroll
      for (int j = 0; j < 4; ++j) acc[r][j] = 0.f;

    for (int cc = 0; cc < 4; ++cc) {
      __syncthreads();
      // stage 256 k x 32 c: granule (k = g>>3, m = g&7); comp u -> col m+8u
      #pragma unroll
      for (int i = 0; i < 8; ++i) {
        int g = t + 256 * i;
        int k = g >> 3, m = g & 7;
        int kpos = k + 4 * (k >> 5);
        float4 v = *(const float4*)(emb + (size_t)(h * 256 + k) * 128 + cc * 32 + m * 4);
        es[(m +  0) * 292 + kpos] = v.x;
        es[(m +  8) * 292 + kpos] = v.y;
        es[(m + 16) * 292 + kpos] = v.z;
        es[(m + 24) * 292 + kpos] = v.w;
      }
      __syncthreads();
      const int hc = cc >> 1;               // which 64-c half of xv
      const int lbase = (cc & 1) * 32;
      #pragma unroll 4
      for (int pc = 0; pc < 32; ++pc) {
        float4 e4 = *(const float4*)&es[pc * 292 + lofs];
        const int li = lbase + 4 * (pc & 7) + (pc >> 3);
        #pragma unroll
        for (int r = 0; r < 8; ++r) {
          float sx = rdl(xv[2*r + hc], li);
          acc[r][0] += sx * e4.x; acc[r][1] += sx * e4.y;
          acc[r][2] += sx * e4.z; acc[r][3] += sx * e4.w;
        }
      }
    }

    // epilogue half h (distances shifted by -||x||^2: argmin/softmax invariant)
    float4 ee4 = *(const float4*)(ee + h * 256 + 4 * lane);
    #pragma unroll
    for (int r = 0; r < 8; ++r) {
      float dd[4];
      dd[0] = ee4.x - 2.f * acc[r][0];
      dd[1] = ee4.y - 2.f * acc[r][1];
      dd[2] = ee4.z - 2.f * acc[r][2];
      dd[3] = ee4.w - 2.f * acc[r][3];
      float ml = dd[0]; int jb = 0;
      #pragma unroll
      for (int j = 1; j < 4; ++j) if (dd[j] < ml) { ml = dd[j]; jb = j; }
      int bkl = h * 256 + 4 * lane + jb;
      #pragma unroll
      for (int o = 32; o; o >>= 1) {
        float om = __shfl_xor(ml, o); int ob = __shfl_xor(bkl, o);
        if (om < ml || (om == ml && ob < bkl)) { ml = om; bkl = ob; }
      }
      float sl = 0.f, tl = 0.f;
      #pragma unroll
      for (int j = 0; j < 4; ++j) {
        float z = ml - dd[j];
        float e = __expf(z);
        sl += e; tl += z * e;
      }
      #pragma unroll
      for (int o = 32; o; o >>= 1) { sl += __shfl_xor(sl, o); tl += __shfl_xor(tl, o); }
      if (h == 0) {
        m0[r] = ml; bk0[r] = bkl; S0[r] = sl; T0[r] = tl;
      } else {
        float mo = m0[r], So = S0[r], To = T0[r];
        if (ml < mo) {                     // new frame ml
          float f = __expf(ml - mo);
          S0[r] = sl + So * f;
          T0[r] = tl + (To + (ml - mo) * So) * f;
          m0[r] = ml; bk0[r] = bkl;
        } else {                           // keep frame mo (ties keep smaller idx)
          float f = __expf(mo - ml);
          S0[r] = So + sl * f;
          T0[r] = To + (tl + (mo - ml) * sl) * f;
        }
      }
    }
  }

  // finalize rows: commit (needs ||x||^2), entropy, idx
  float commit_acc = 0.f, ent_acc = 0.f;
  #pragma unroll
  for (int r = 0; r < 8; ++r) {
    float p = xv[2*r] * xv[2*r] + xv[2*r+1] * xv[2*r+1];
    #pragma unroll
    for (int o = 32; o; o >>= 1) p += __shfl_xor(p, o);
    if (lane == 0) {
      int rn = n0 + wave * 8 + r;
      out[IDX_OFF + rn] = (float)bk0[r];
      idxws[rn] = (float)bk0[r];
      ibk[wave * 8 + r] = bk0[r];
      commit_acc += p + m0[r];
      ent_acc    += T0[r] / S0[r] - __logf(S0[r]);
    }
  }
  if (lane == 0) { red[wave] = commit_acc; red[4 + wave] = ent_acc; }
  __syncthreads();
  if (t == 0) {
    unsafeAtomicAdd(&sums[0], red[0] + red[1] + red[2] + red[3]);
    unsafeAtomicAdd(&sums[1], red[4] + red[5] + red[6] + red[7]);
  }

  // fused gather: eq[r][c] = emb[bk_r][c] (reuse smem as [32][132])
  {
    const int r = t & 31, c0 = (t >> 5) * 16;
    const int kq = ibk[r];
    const float* src = emb + (size_t)kq * 128 + c0;
    float4 v0 = *(const float4*)(src);
    float4 v1 = *(const float4*)(src + 4);
    float4 v2 = *(const float4*)(src + 8);
    float4 v3 = *(const float4*)(src + 12);
    float* dst = &xs[r * 132 + c0];
    *(float4*)(dst) = v0; *(float4*)(dst+4) = v1;
    *(float4*)(dst+8) = v2; *(float4*)(dst+12) = v3;
  }
  __syncthreads();
  {
    const int l7 = t & 7;
    #pragma unroll
    for (int pp = 0; pp < 4; ++pp) {
      int c = (t >> 3) + 32 * pp;
      float4 v;
      v.x = xs[(4*l7 + 0) * 132 + c];
      v.y = xs[(4*l7 + 1) * 132 + c];
      v.z = xs[(4*l7 + 2) * 132 + c];
      v.w = xs[(4*l7 + 3) * 132 + c];
      *(float4*)(out + ((size_t)b * 128 + c) * 32768 + s0 + 4 * l7) = v;
    }
  }
}

// dw scatter: block = (row-split s, 8-channel slice ccB), grid = 16*S
__global__ __launch_bounds__(256) void scatter_kernel(
    const float* __restrict__ inputs, const float* __restrict__ idxws,
    float* __restrict__ partial, float* __restrict__ cpart, int S)
{
  __shared__ float acc[512 * 9];
  __shared__ float cnts[512];
  const int t = threadIdx.x;
  const int s = blockIdx.x >> 4, ccB = blockIdx.x & 15;
  const int R = 65536 / S;
  for (int m = t; m < 512 * 9; m += 256) acc[m] = 0.f;
  if (ccB == 0) for (int m = t; m < 512; m += 256) cnts[m] = 0.f;
  __syncthreads();
  const int l = t & 63, cg = t >> 6;
  for (int it = 0; it < R / 256; ++it) {
    int n = s * R + it * 256;
    int bb = n >> 15;
    int sp = (n & 32767) + 4 * l;
    float4 i4 = *(const float4*)(idxws + n + 4 * l);
    int k0 = (int)i4.x, k1 = (int)i4.y, k2 = (int)i4.z, k3 = (int)i4.w;
    #pragma unroll
    for (int ci = 0; ci < 2; ++ci) {
      int c = cg * 2 + ci;
      float4 x4 = *(const float4*)(inputs + ((size_t)bb * 128 + ccB * 8 + c) * 32768 + sp);
      atomicAdd(&acc[k0 * 9 + c], x4.x);
      atomicAdd(&acc[k1 * 9 + c], x4.y);
      atomicAdd(&acc[k2 * 9 + c], x4.z);
      atomicAdd(&acc[k3 * 9 + c], x4.w);
    }
    if (ccB == 0 && cg == 0) {
      atomicAdd(&cnts[k0], 1.f); atomicAdd(&cnts[k1], 1.f);
      atomicAdd(&cnts[k2], 1.f); atomicAdd(&cnts[k3], 1.f);
    }
  }
  __syncthreads();
  for (int m = t; m < 512 * 8; m += 256) {
    int k = m >> 3, c = m & 7;
    partial[(size_t)s * 65536 + k * 128 + ccB * 8 + c] = acc[k * 9 + c];
  }
  if (ccB == 0) for (int m = t; m < 512; m += 256) cpart[s * 512 + m] = cnts[m];
}

// finalize scalars
__global__ __launch_bounds__(512) void c1_kernel(const float* __restrict__ ecs,
    const float* __restrict__ cpart, const float* __restrict__ sums,
    float* __restrict__ invs, float* __restrict__ out, int S)
{
  __shared__ float sred[512];
  int t = threadIdx.x;
  float cnt = 0.f;
  for (int s = 0; s < S; ++s) cnt += cpart[s * 512 + t];
  float cn = 0.99f * ecs[t] + 0.01f * cnt;
  out[NCS_OFF + t] = cn;
  sred[t] = cn;
  __syncthreads();
  for (int o = 256; o; o >>= 1) {
    if (t < o) sred[t] += sred[t + o];
    __syncthreads();
  }
  float ntot = sred[0];
  float sm = (cn + 1e-5f) / (ntot + 0.00512f) * ntot;
  invs[t] = 1.f / sm;
  if (t == 0)
    out[LOSS_OFF] = 0.25f * sums[0] / 8388608.f - 0.01f * sums[1] / 65536.f;
}

// EMA weight update + normalized embedding (reduces S partials)
__global__ __launch_bounds__(256) void c2_kernel(const float* __restrict__ emaw,
    const float* __restrict__ partial, const float* __restrict__ invs,
    float* __restrict__ out, int S)
{
  int i = blockIdx.x * 256 + threadIdx.x;
  float dwv = 0.f;
  for (int s = 0; s < S; ++s) dwv += partial[(size_t)s * 65536 + i];
  float val = 0.99f * emaw[i] + 0.01f * dwv;
  out[EMAW_OFF + i] = val;
  out[EMB_OFF + i] = val * invs[i >> 7];
}

extern "C" void kernel_launch(void* const* d_in, const int* in_sizes, int n_in,
                              void* d_out, int out_size, void* d_ws, size_t ws_size,
                              hipStream_t stream) {
  const float* inputs = (const float*)d_in[0];
  const float* emb    = (const float*)d_in[1];
  const float* ecs    = (const float*)d_in[2];
  const float* emaw   = (const float*)d_in[3];
  float* out = (float*)d_out;
  float* wsf = (float*)d_ws;
  (void)in_sizes; (void)n_in; (void)out_size;

  size_t wsfl = ws_size / 4;
  int S = 32;
  while (S > 1 && (size_t)S * 66048 + 66592 > wsfl) S >>= 1;

  float* partial = wsf;
  float* cpart   = partial + (size_t)S * 65536;
  float* idxws   = cpart + (size_t)S * 512;
  float* sums    = idxws + 65536;
  float* ee      = sums + 16;
  float* invs    = ee + 512;

  hipMemsetAsync(sums, 0, 16 * sizeof(float), stream);
  ee_kernel     <<<8,      256, 0, stream>>>(emb, ee);
  dist_kernel   <<<2048,   256, 0, stream>>>(inputs, emb, ee, out, idxws, sums);
  scatter_kernel<<<16 * S, 256, 0, stream>>>(inputs, idxws, partial, cpart, S);
  c1_kernel     <<<1,      512, 0, stream>>>(ecs, cpart, sums, invs, out, S);
  c2_kernel     <<<256,    256, 0, stream>>>(emaw, partial, invs, out, S);
}